// Round 1
// baseline (867.725 us; speedup 1.0000x reference)
//
#include <hip/hip_runtime.h>
#include <stdint.h>

// Problem: B=64, DIM=512, T=2048, S=1024.
// out[b][s][t] = softmax_s( 2*cross - msq[s] ),  cross = sum_d units[d][s]*H[b][d][t].
// Pipeline:
//   k_prep_units: units fp32 -> U^T bf16 hi/lo [s][d] in ws, + msq[s].
//   k_prep_h:     H fp32 [b][d][t] -> H^T bf16 hi/lo [b][t][d] in ws (LDS transpose).
//   k_gemm:       G[s][t] = U^T * H_b via 3x bf16 MFMA (hi/lo split), raw logits -> d_out.
//   k_softmax:    in-place softmax over s (16 t-columns per block, logits held in regs).
// ws layout (bytes): Hh[0,128M) Hl[128M,256M) Uh Ul msq  => total 270,536,704 B.

typedef unsigned short u16;
typedef __attribute__((ext_vector_type(8))) short short8;   // 8 x bf16 (guide-verified frag type)
typedef __attribute__((ext_vector_type(4))) float f32x4;

#define B_DIM 64
#define DIM   512
#define T_DIM 2048
#define S_DIM 1024

__device__ __forceinline__ u16 f32_to_bf16(float f) {
  uint32_t u = __float_as_uint(f);
  uint32_t r = u + 0x7FFFu + ((u >> 16) & 1u);   // RNE
  return (u16)(r >> 16);
}
__device__ __forceinline__ float bf16_to_f32(u16 h) {
  return __uint_as_float(((uint32_t)h) << 16);
}

// ---------------- K0a: units -> U^T hi/lo + msq ----------------
__global__ __launch_bounds__(256) void k_prep_units(const float* __restrict__ units,
                                                    u16* __restrict__ Uh, u16* __restrict__ Ul,
                                                    float* __restrict__ msq) {
  const int s0 = blockIdx.x * 4;          // 256 blocks cover S=1024
  const int tid = threadIdx.x;
  const int lane = tid & 63, wv = tid >> 6;
  float acc0 = 0.f, acc1 = 0.f, acc2 = 0.f, acc3 = 0.f;
#pragma unroll
  for (int j = 0; j < 2; ++j) {
    const int d = tid + j * 256;
    const float4 v = *(const float4*)(units + (size_t)d * S_DIM + s0);
    acc0 += v.x * v.x; acc1 += v.y * v.y; acc2 += v.z * v.z; acc3 += v.w * v.w;
    const float f0 = v.x, f1 = v.y, f2 = v.z, f3 = v.w;
    u16 h;
    h = f32_to_bf16(f0); Uh[(s0 + 0) * DIM + d] = h; Ul[(s0 + 0) * DIM + d] = f32_to_bf16(f0 - bf16_to_f32(h));
    h = f32_to_bf16(f1); Uh[(s0 + 1) * DIM + d] = h; Ul[(s0 + 1) * DIM + d] = f32_to_bf16(f1 - bf16_to_f32(h));
    h = f32_to_bf16(f2); Uh[(s0 + 2) * DIM + d] = h; Ul[(s0 + 2) * DIM + d] = f32_to_bf16(f2 - bf16_to_f32(h));
    h = f32_to_bf16(f3); Uh[(s0 + 3) * DIM + d] = h; Ul[(s0 + 3) * DIM + d] = f32_to_bf16(f3 - bf16_to_f32(h));
  }
#pragma unroll
  for (int off = 1; off < 64; off <<= 1) {
    acc0 += __shfl_xor(acc0, off);
    acc1 += __shfl_xor(acc1, off);
    acc2 += __shfl_xor(acc2, off);
    acc3 += __shfl_xor(acc3, off);
  }
  __shared__ float part[4][4];
  if (lane == 0) { part[wv][0] = acc0; part[wv][1] = acc1; part[wv][2] = acc2; part[wv][3] = acc3; }
  __syncthreads();
  if (tid < 4) msq[s0 + tid] = part[0][tid] + part[1][tid] + part[2][tid] + part[3][tid];
}

// ---------------- K0b: H [b][d][t] -> H^T hi/lo [b][t][d] ----------------
__global__ __launch_bounds__(256) void k_prep_h(const float* __restrict__ H,
                                                u16* __restrict__ Hh, u16* __restrict__ Hl) {
  __shared__ float tile[64 * 68];                 // [d-local][t-local], pad 68 to spread banks
  const int t0 = blockIdx.x * 64, d0 = blockIdx.y * 64, b = blockIdx.z;
  const int tid = threadIdx.x;
#pragma unroll
  for (int j = 0; j < 4; ++j) {
    const int chunk = tid + j * 256;
    const int r = chunk >> 4, c4 = (chunk & 15) * 4;
    const float4 v = *(const float4*)(H + ((size_t)(b * DIM + d0 + r)) * T_DIM + t0 + c4);
    *(float4*)(&tile[r * 68 + c4]) = v;
  }
  __syncthreads();
#pragma unroll
  for (int j = 0; j < 2; ++j) {
    const int chunk = tid + j * 256;
    const int q = chunk >> 3, e8 = (chunk & 7) * 8;   // output row t0+q, d-chunk e8
    union { u16 us[8]; uint4 v4; } hi, lo;
#pragma unroll
    for (int k = 0; k < 8; ++k) {
      const float f = tile[(e8 + k) * 68 + q];
      const u16 h = f32_to_bf16(f);
      hi.us[k] = h;
      lo.us[k] = f32_to_bf16(f - bf16_to_f32(h));
    }
    const size_t o = ((size_t)(b * T_DIM + t0 + q)) * DIM + d0 + e8;
    *(uint4*)(Hh + o) = hi.v4;
    *(uint4*)(Hl + o) = lo.v4;
  }
}

// ---------------- K1: GEMM (128x128 tile, BK=32, 3x bf16 MFMA) ----------------
__device__ __forceinline__ void gl_lds16(const void* g, void* l) {
  __builtin_amdgcn_global_load_lds((const __attribute__((address_space(1))) void*)g,
                                   (__attribute__((address_space(3))) void*)l, 16, 0, 0);
}

__global__ __launch_bounds__(256, 3) void k_gemm(const u16* __restrict__ Uh, const u16* __restrict__ Ul,
                                                 const u16* __restrict__ Hh, const u16* __restrict__ Hl,
                                                 float* __restrict__ out) {
  // LDS: Ah @0, Al @8192, Bh @16384, Bl @24576 ; each tile [128 rows][32 k] bf16 (64 B rows, linear)
  __shared__ char smem[32768];
  const int tid = threadIdx.x;
  const int lane = tid & 63, wv = tid >> 6;
  const int s0 = blockIdx.x * 128, t0 = blockIdx.y * 128, b = blockIdx.z;
  const int wrow = (wv >> 1) * 64, wcol = (wv & 1) * 64;   // wave -> 64x64 subtile

  // Staging: 512 16B-chunks per array; thread does chunks tid and tid+256.
  // Source address carries the XOR swizzle (LDS dest stays linear: chunk*16).
  const int ch0 = tid, ch1 = tid + 256;
  const int r0 = ch0 >> 2, r1 = ch1 >> 2;
  const int cs0 = (ch0 & 3) ^ ((r0 >> 1) & 3);
  const int cs1 = (ch1 & 3) ^ ((r1 >> 1) & 3);
  const size_t aOff0 = (size_t)(s0 + r0) * 1024 + (size_t)cs0 * 16;   // row stride = 512*2B
  const size_t aOff1 = (size_t)(s0 + r1) * 1024 + (size_t)cs1 * 16;
  const size_t bOff0 = (size_t)(b * T_DIM + t0 + r0) * 1024 + (size_t)cs0 * 16;
  const size_t bOff1 = (size_t)(b * T_DIM + t0 + r1) * 1024 + (size_t)cs1 * 16;
  char* const dst0 = smem + ch0 * 16;
  char* const dst1 = smem + ch1 * 16;

  // Fragment read offsets (constant across K-loop): row*64 + (chunk ^ swz(row))*16
  int offA[4], offB[4];
#pragma unroll
  for (int mt = 0; mt < 4; ++mt) {
    const int row = wrow + mt * 16 + (lane & 15);
    const int cidx = (lane >> 4) ^ ((row >> 1) & 3);
    offA[mt] = row * 64 + cidx * 16;
  }
#pragma unroll
  for (int nt = 0; nt < 4; ++nt) {
    const int row = wcol + nt * 16 + (lane & 15);
    const int cidx = (lane >> 4) ^ ((row >> 1) & 3);
    offB[nt] = 16384 + row * 64 + cidx * 16;
  }

  f32x4 acc[4][4];
#pragma unroll
  for (int i = 0; i < 4; ++i)
#pragma unroll
    for (int j = 0; j < 4; ++j)
      acc[i][j] = (f32x4){0.f, 0.f, 0.f, 0.f};

  const char* const pUh = (const char*)Uh;
  const char* const pUl = (const char*)Ul;
  const char* const pHh = (const char*)Hh;
  const char* const pHl = (const char*)Hl;

  for (int kt = 0; kt < 16; ++kt) {
    const size_t ko = (size_t)kt * 64;            // 32 bf16 = 64 B per K-step
    gl_lds16(pUh + aOff0 + ko, dst0);
    gl_lds16(pUh + aOff1 + ko, dst1);
    gl_lds16(pUl + aOff0 + ko, dst0 + 8192);
    gl_lds16(pUl + aOff1 + ko, dst1 + 8192);
    gl_lds16(pHh + bOff0 + ko, dst0 + 16384);
    gl_lds16(pHh + bOff1 + ko, dst1 + 16384);
    gl_lds16(pHl + bOff0 + ko, dst0 + 24576);
    gl_lds16(pHl + bOff1 + ko, dst1 + 24576);
    __syncthreads();                               // drains vmcnt: LDS tiles ready

    short8 ah[4], al[4], bh[4], bl[4];
#pragma unroll
    for (int i = 0; i < 4; ++i) {
      ah[i] = *(const short8*)(smem + offA[i]);
      al[i] = *(const short8*)(smem + offA[i] + 8192);
      bh[i] = *(const short8*)(smem + offB[i]);
      bl[i] = *(const short8*)(smem + offB[i] + 8192);
    }
#pragma unroll
    for (int mt = 0; mt < 4; ++mt)
#pragma unroll
      for (int nt = 0; nt < 4; ++nt) {
        acc[mt][nt] = __builtin_amdgcn_mfma_f32_16x16x32_bf16(ah[mt], bh[nt], acc[mt][nt], 0, 0, 0);
        acc[mt][nt] = __builtin_amdgcn_mfma_f32_16x16x32_bf16(ah[mt], bl[nt], acc[mt][nt], 0, 0, 0);
        acc[mt][nt] = __builtin_amdgcn_mfma_f32_16x16x32_bf16(al[mt], bh[nt], acc[mt][nt], 0, 0, 0);
      }
    __syncthreads();                               // protect LDS before next stage
  }

  // C/D 16x16x32: col = lane&15, row = (lane>>4)*4 + reg  [m89/m91]
  float* const outb = out + (size_t)b * ((size_t)S_DIM * T_DIM);
  const int tcol0 = t0 + wcol + (lane & 15);
  const int sbase = s0 + wrow + (lane >> 4) * 4;
#pragma unroll
  for (int mt = 0; mt < 4; ++mt)
#pragma unroll
    for (int nt = 0; nt < 4; ++nt)
#pragma unroll
      for (int r = 0; r < 4; ++r) {
        const int srow = sbase + mt * 16 + r;
        outb[(size_t)srow * T_DIM + tcol0 + nt * 16] = acc[mt][nt][r];
      }
}

// ---------------- K2: in-place softmax over s ----------------
__global__ __launch_bounds__(256) void k_softmax(float* __restrict__ out, const float* __restrict__ msq) {
  const int t0 = blockIdx.x * 16, b = blockIdx.y;
  const int tid = threadIdx.x;
  const int lane = tid & 63, wv = tid >> 6;
  const int c = tid & 3;          // column quad (4 t-columns per thread)
  const int g = tid >> 2;         // s-stride group: s = g + 64*i
  float* const base = out + (size_t)b * ((size_t)S_DIM * T_DIM) + t0 + c * 4;

  float4 l[16];
  float4 m = {-3.0e38f, -3.0e38f, -3.0e38f, -3.0e38f};
#pragma unroll
  for (int i = 0; i < 16; ++i) {
    const int s = g + i * 64;
    const float4 v = *(const float4*)(base + (size_t)s * T_DIM);
    const float mq = msq[s];
    float4 L;
    L.x = 2.f * v.x - mq; L.y = 2.f * v.y - mq; L.z = 2.f * v.z - mq; L.w = 2.f * v.w - mq;
    l[i] = L;
    m.x = fmaxf(m.x, L.x); m.y = fmaxf(m.y, L.y); m.z = fmaxf(m.z, L.z); m.w = fmaxf(m.w, L.w);
  }
  // reduce over lanes sharing c (xor bits 2..5), then across waves via LDS
#pragma unroll
  for (int off = 4; off < 64; off <<= 1) {
    m.x = fmaxf(m.x, __shfl_xor(m.x, off));
    m.y = fmaxf(m.y, __shfl_xor(m.y, off));
    m.z = fmaxf(m.z, __shfl_xor(m.z, off));
    m.w = fmaxf(m.w, __shfl_xor(m.w, off));
  }
  __shared__ float4 redM[4][4];
  __shared__ float4 redS[4][4];
  if (lane < 4) redM[wv][lane] = m;
  __syncthreads();
  float4 M = redM[0][c];
#pragma unroll
  for (int w = 1; w < 4; ++w) {
    const float4 o = redM[w][c];
    M.x = fmaxf(M.x, o.x); M.y = fmaxf(M.y, o.y); M.z = fmaxf(M.z, o.z); M.w = fmaxf(M.w, o.w);
  }
  float4 ssum = {0.f, 0.f, 0.f, 0.f};
#pragma unroll
  for (int i = 0; i < 16; ++i) {
    float4 e;
    e.x = __expf(l[i].x - M.x);
    e.y = __expf(l[i].y - M.y);
    e.z = __expf(l[i].z - M.z);
    e.w = __expf(l[i].w - M.w);
    l[i] = e;
    ssum.x += e.x; ssum.y += e.y; ssum.z += e.z; ssum.w += e.w;
  }
#pragma unroll
  for (int off = 4; off < 64; off <<= 1) {
    ssum.x += __shfl_xor(ssum.x, off);
    ssum.y += __shfl_xor(ssum.y, off);
    ssum.z += __shfl_xor(ssum.z, off);
    ssum.w += __shfl_xor(ssum.w, off);
  }
  if (lane < 4) redS[wv][lane] = ssum;
  __syncthreads();
  float4 S = redS[0][c];
#pragma unroll
  for (int w = 1; w < 4; ++w) {
    const float4 o = redS[w][c];
    S.x += o.x; S.y += o.y; S.z += o.z; S.w += o.w;
  }
  float4 rs;
  rs.x = 1.0f / S.x; rs.y = 1.0f / S.y; rs.z = 1.0f / S.z; rs.w = 1.0f / S.w;
#pragma unroll
  for (int i = 0; i < 16; ++i) {
    const int s = g + i * 64;
    float4 o;
    o.x = l[i].x * rs.x; o.y = l[i].y * rs.y; o.z = l[i].z * rs.z; o.w = l[i].w * rs.w;
    *(float4*)(base + (size_t)s * T_DIM) = o;
  }
}

// ---------------- launch ----------------
extern "C" void kernel_launch(void* const* d_in, const int* in_sizes, int n_in,
                              void* d_out, int out_size, void* d_ws, size_t ws_size,
                              hipStream_t stream) {
  (void)in_sizes; (void)n_in; (void)out_size;
  const float* H = (const float*)d_in[0];
  const float* units = (const float*)d_in[1];
  float* out = (float*)d_out;
  char* ws = (char*)d_ws;
  // ws layout (needs ~258 MiB; assumed available)
  u16* Hh = (u16*)(ws);
  u16* Hl = (u16*)(ws + 134217728);
  u16* Uh = (u16*)(ws + 268435456);
  u16* Ul = (u16*)(ws + 269484032);
  float* msq = (float*)(ws + 270532608);
  (void)ws_size;

  k_prep_units<<<dim3(S_DIM / 4), 256, 0, stream>>>(units, Uh, Ul, msq);
  k_prep_h<<<dim3(T_DIM / 64, DIM / 64, B_DIM), 256, 0, stream>>>(H, Hh, Hl);
  k_gemm<<<dim3(S_DIM / 128, T_DIM / 128, B_DIM), 256, 0, stream>>>(Uh, Ul, Hh, Hl, out);
  k_softmax<<<dim3(T_DIM / 16, B_DIM), 256, 0, stream>>>(out, msq);
}